// Round 8
// baseline (244.012 us; speedup 1.0000x reference)
//
#include <hip/hip_runtime.h>
#include <hip/hip_bf16.h>
#include <cmath>
#include <cstdint>

#define NNODES 2048
#define NEDGES 8192
#define NCH 64
#define NHID 64
#define NPATH 34
#define NTASK (NPATH * NCH)   // 2176
#define CGTOT 3436
#define MROW 9984
#define TT3 1028              // padded T slots (l-rows padded to 4 or 8)
#define EBLK 8                // edges per LDS chunk
#define GLEN_MAX 564

#define MI_BYTES ((size_t)NNODES * MROW * 2)          // 40,894,464
#define XT_BYTES ((size_t)NNODES * 16 * NCH * 2)      //  4,194,304
#define WT_BYTES ((size_t)64 * NTASK * 2)             //    278,528 (bf16 Wt)
#define OFF_OFF  (MI_BYTES)
#define CUR_OFF  (OFF_OFF + 2052 * 4)
#define PACK_OFF (CUR_OFF + 2048 * 4)
#define ORD_OFF  (PACK_OFF + 8192 * 4)
#define XT_OFF   (ORD_OFF + 2048 * 4)
#define WT_OFF   (XT_OFF + XT_BYTES)
#define CGP_OFF  (WT_OFF + WT_BYTES)
#define CGP_FLOATS (TT3 * 9)                          // 1028*8 CGT2 + 1028 meta

typedef __attribute__((ext_vector_type(8))) short short8;
typedef __attribute__((ext_vector_type(4))) float floatx4;

// ---------------- path tables (compile-time) ----------------
struct PathTables {
  int l1[NPATH], l2[NPATH], l3[NPATH];
  int cg_off[NPATH], t_off3[NPATH], rank[NPATH];
  int gpaths[2][20], gnp[2], gbase3[2], glen3[2];
  int cg_total, tt3, npaths;
};

constexpr PathTables make_tables() {
  PathTables tb{};
  int np = 0;
  for (int a = 0; a < 4; ++a)
    for (int b = 0; b < 4; ++b) {
      int lo = a > b ? a - b : b - a;
      int hi = a + b < 3 ? a + b : 3;
      for (int c = lo; c <= hi; ++c) { tb.l1[np] = a; tb.l2[np] = b; tb.l3[np] = c; ++np; }
    }
  int cg = 0;
  int cnt[4] = {0, 0, 0, 0};
  for (int i = 0; i < np; ++i) {
    tb.cg_off[i] = cg; tb.rank[i] = cnt[tb.l3[i]]++;
    cg += (2 * tb.l1[i] + 1) * (2 * tb.l2[i] + 1) * (2 * tb.l3[i] + 1);
  }
  // group 0: l3 in {0,3}; group 1: l3 in {1,2}. l-rows padded to 4 (d3<=3) or 8.
  int tt = 0;
  for (int g = 0; g < 2; ++g) {
    tb.gbase3[g] = tt;
    for (int i = 0; i < np; ++i) {
      int gi = (tb.l3[i] == 0 || tb.l3[i] == 3) ? 0 : 1;
      if (gi != g) continue;
      tb.gpaths[g][tb.gnp[g]++] = i;
      tb.t_off3[i] = tt;
      int d1 = 2 * tb.l1[i] + 1, d3 = 2 * tb.l3[i] + 1;
      int st = (d3 <= 4) ? 4 : 8;
      tt += d1 * st;
    }
    tb.glen3[g] = tt - tb.gbase3[g];
  }
  tb.cg_total = cg; tb.tt3 = tt; tb.npaths = np;
  return tb;
}

constexpr PathTables H_TB = make_tables();
static_assert(H_TB.npaths == NPATH, "npaths");
static_assert(H_TB.cg_total == CGTOT, "cgtot");
static_assert(H_TB.tt3 == TT3, "tt3");
static_assert(H_TB.gnp[0] == 14 && H_TB.gnp[1] == 20, "gnp");
static_assert(H_TB.gbase3[1] == 464 && H_TB.glen3[0] == 464 && H_TB.glen3[1] == 564, "gsplit");

__constant__ PathTables d_tb = make_tables();

// ---------------- NumPy legacy RandomState(1234) reproduction (host) ----------------
namespace {
struct MT19937 {
  uint32_t mt[624]; int mti; bool has_g; double gval;
  void seed(uint32_t s) {
    for (int i = 0; i < 624; ++i) { mt[i] = s; s = 1812433253u * (s ^ (s >> 30)) + (uint32_t)i + 1u; }
    mti = 624; has_g = false; gval = 0.0;
  }
  uint32_t next() {
    if (mti >= 624) {
      for (int i = 0; i < 624; ++i) {
        uint32_t y = (mt[i] & 0x80000000u) | (mt[(i + 1) % 624] & 0x7fffffffu);
        mt[i] = mt[(i + 397) % 624] ^ (y >> 1) ^ ((y & 1u) ? 0x9908b0dfu : 0u);
      }
      mti = 0;
    }
    uint32_t y = mt[mti++];
    y ^= y >> 11; y ^= (y << 7) & 0x9d2c5680u; y ^= (y << 15) & 0xefc60000u; y ^= y >> 18;
    return y;
  }
  double rdbl() {
    uint32_t a = next() >> 5, b = next() >> 6;
    return ((double)a * 67108864.0 + (double)b) / 9007199254740992.0;
  }
  double gauss() {
    if (has_g) { has_g = false; return gval; }
    double x1, x2, r2;
    do {
      x1 = 2.0 * rdbl() - 1.0;
      x2 = 2.0 * rdbl() - 1.0;
      r2 = x1 * x1 + x2 * x2;
    } while (r2 >= 1.0 || r2 == 0.0);
    double f = std::sqrt(-2.0 * std::log(r2) / r2);
    gval = f * x1; has_g = true;
    return f * x2;
  }
};

float host_pack[CGP_FLOATS];
float* g_cg_dev = nullptr;
bool g_cg_ok = false;

struct CGInit {
  CGInit() {
    static float cg[CGTOT];
    MT19937 g; g.seed(1234u);
    int idx = 0;
    for (int i = 0; i < NPATH; ++i) {
      int d1 = 2 * H_TB.l1[i] + 1, d2 = 2 * H_TB.l2[i] + 1, d3 = 2 * H_TB.l3[i] + 1;
      int sz = d1 * d2 * d3;
      for (int k = 0; k < sz; ++k) cg[idx++] = (float)(g.gauss() * 0.2);
    }
    const int ybase[4] = {0, 1, 4, 9};
    for (int k = 0; k < CGP_FLOATS; ++k) host_pack[k] = 0.f;   // pad slots: zero cg
    for (int i = 0; i < NPATH; ++i) {
      int d1 = 2 * H_TB.l1[i] + 1, d2 = 2 * H_TB.l2[i] + 1, d3 = 2 * H_TB.l3[i] + 1;
      int st = (d3 <= 4) ? 4 : 8;
      for (int l = 0; l < d1; ++l)
        for (int n3 = 0; n3 < d3; ++n3) {
          int slot = H_TB.t_off3[i] + l * st + n3;
          for (int m = 0; m < d2; ++m)
            host_pack[slot * 8 + m] = cg[H_TB.cg_off[i] + l * d2 * d3 + m * d3 + n3];
          host_pack[TT3 * 8 + slot] = (float)ybase[H_TB.l2[i]];
        }
    }
    (void)hipHostRegister(host_pack, sizeof(host_pack), hipHostRegisterDefault);
    void* p = nullptr;
    if (hipMalloc(&p, sizeof(host_pack)) == hipSuccess && p) {
      if (hipMemcpy(p, host_pack, sizeof(host_pack), hipMemcpyHostToDevice) == hipSuccess) {
        float back = -1.f;
        if (hipMemcpy(&back, (float*)p + (CGP_FLOATS - 1), sizeof(float),
                      hipMemcpyDeviceToHost) == hipSuccess && back == host_pack[CGP_FLOATS - 1]) {
          g_cg_dev = (float*)p;
          g_cg_ok = true;
        }
      }
    }
  }
} cg_init_instance;
}  // namespace

__device__ __forceinline__ float bf2f(unsigned short u) {
  union { unsigned int i; float f; } v; v.i = ((unsigned int)u) << 16; return v.f;
}
__device__ __forceinline__ unsigned short f2bf(float f) {
  __hip_bfloat16 h = __float2bfloat16(f);
  union { __hip_bfloat16 h; unsigned short u; } v; v.h = h; return v.u;
}

// ---------------- kernel A: CSR degrees + prefix + degree-descending order ----------------
__global__ __launch_bounds__(1024) void scan_kernel(
    const int* __restrict__ edge_index, int* __restrict__ off, int* __restrict__ cursor,
    int* __restrict__ order)
{
  __shared__ int ldeg[NNODES];
  __shared__ int csum[1024];
  __shared__ int hist[64];
  const int t = threadIdx.x;
  for (int i = t; i < NNODES; i += 1024) ldeg[i] = 0;
  __syncthreads();
  const int* __restrict__ dsts = edge_index + NEDGES;
  for (int e = t; e < NEDGES; e += 1024) atomicAdd(&ldeg[dsts[e]], 1);
  __syncthreads();
  const int l0 = ldeg[2 * t], l1 = ldeg[2 * t + 1];
  const int s = l0 + l1;
  csum[t] = s;
  __syncthreads();
  for (int o = 1; o < 1024; o <<= 1) {
    int v = (t >= o) ? csum[t - o] : 0;
    __syncthreads();
    csum[t] += v;
    __syncthreads();
  }
  int run = csum[t] - s;
  off[2 * t] = run; cursor[2 * t] = run;
  off[2 * t + 1] = run + l0; cursor[2 * t + 1] = run + l0;
  if (t == 0) off[NNODES] = NEDGES;
  if (t < 64) hist[t] = 0;
  __syncthreads();
  for (int i = t; i < NNODES; i += 1024) {
    int d = ldeg[i]; d = d > 63 ? 63 : d;
    atomicAdd(&hist[63 - d], 1);
  }
  __syncthreads();
  if (t == 0) { int r2 = 0; for (int b = 0; b < 64; ++b) { int c = hist[b]; hist[b] = r2; r2 += c; } }
  __syncthreads();
  for (int i = t; i < NNODES; i += 1024) {
    int d = ldeg[i]; d = d > 63 ? 63 : d;
    int pos = atomicAdd(&hist[63 - d], 1);
    order[pos] = i;
  }
}

// ---------------- kernel B: CSR fill + xT build + Wt (bf16 transposed W) build ----------------
__global__ __launch_bounds__(256) void fill_xt_kernel(
    const int* __restrict__ edge_index, int* __restrict__ cursor, int* __restrict__ pack,
    const float* __restrict__ x0, const float* __restrict__ x1,
    const float* __restrict__ x2, const float* __restrict__ x3,
    const float* __restrict__ wl0, const float* __restrict__ wl1,
    const float* __restrict__ wl2, const float* __restrict__ wl3,
    __hip_bfloat16* __restrict__ xT, unsigned short* __restrict__ wt_all)
{
  const int b = blockIdx.x;
  const int t = threadIdx.x;
  if (b < 32) {
    const int e = b * 256 + t;
    const int d = edge_index[NEDGES + e];
    const int s = edge_index[e];
    const int pos = atomicAdd(&cursor[d], 1);
    pack[pos] = e | (s << 13);
  } else if (b < 32 + NNODES) {
    const int n = b - 32;
    for (int idx = t; idx < 1024; idx += 256) {
      const int j = idx >> 6, c = idx & 63;
      const float* src; int d1, m;
      if (j < 1)      { src = x0; d1 = 1; m = j; }
      else if (j < 4) { src = x1; d1 = 3; m = j - 1; }
      else if (j < 9) { src = x2; d1 = 5; m = j - 4; }
      else            { src = x3; d1 = 7; m = j - 9; }
      const float v = src[((size_t)n * NCH + c) * d1 + m];
      xT[((size_t)n * 16 + j) * NCH + c] = __float2bfloat16(v);
    }
  } else {
    // Wt: transpose+convert W to bf16: Wt_l3[h][k]; 544 blocks x (64h x 4k)
    const int b3 = b - (32 + NNODES);
    const int k = b3 * 4 + (t >> 6);
    const int h = t & 63;
    const float* src; int K, base, kl;
    if (k < 256)       { src = wl0; K = 256; base = 0;     kl = k; }
    else if (k < 832)  { src = wl1; K = 576; base = 16384; kl = k - 256; }
    else if (k < 1536) { src = wl2; K = 704; base = 53248; kl = k - 832; }
    else               { src = wl3; K = 640; base = 98304; kl = k - 1536; }
    wt_all[base + h * K + kl] = f2bf(src[(size_t)kl * 64 + h]);
  }
}

// ---------------- kernel 1: per-node TP, in-kernel T (padded rows), LDS-staged ----------------
template <int D1, int D3>
__device__ __forceinline__ void tp_task_run(
    int wcol, int toff_l, int rank, int nb, const int* __restrict__ epk,
    const float (*Ts)[GLEN_MAX], const float* __restrict__ ws,
    const unsigned short* __restrict__ xT,
    int n, bool first, __hip_bfloat16* __restrict__ m_out)
{
  constexpr int Kc = (D3 == 1) ? 256 : (D3 == 3) ? 576 : (D3 == 5) ? 704 : 640;
  constexpr int Rc = (D3 == 1) ? 0 : (D3 == 3) ? 256 : (D3 == 5) ? 1984 : 5504;
  constexpr int JB = (D1 == 1) ? 0 : (D1 == 3) ? 1 : (D1 == 5) ? 4 : 9;
  constexpr int ST = (D3 <= 4) ? 4 : 8;   // padded l-row stride (16B-aligned)
  const int c = wcol & 63;

  float wv_[EBLK];
#pragma unroll
  for (int ei = 0; ei < EBLK; ++ei)
    wv_[ei] = (ei < nb) ? ws[(size_t)(epk[ei] & 8191) * NTASK + wcol] : 0.f;

  float acc[D3];
#pragma unroll
  for (int m = 0; m < D3; ++m) acc[m] = 0.f;

  for (int ei = 0; ei < nb; ++ei) {
    const int s = epk[ei] >> 13;
    const unsigned short* __restrict__ xr = xT + ((size_t)s * 16 + JB) * NCH + c;
    const float* __restrict__ Tp = &Ts[ei][toff_l];
    float u[D3];
#pragma unroll
    for (int m = 0; m < D3; ++m) u[m] = 0.f;
#pragma unroll
    for (int l = 0; l < D1; ++l) {
      const float xv = bf2f(xr[l * NCH]);
      const floatx4 r0 = *(const floatx4*)(Tp + l * ST);     // ds_read_b128
      floatx4 r1;
      if (D3 > 4) r1 = *(const floatx4*)(Tp + l * ST + 4);
#pragma unroll
      for (int m = 0; m < D3; ++m)
        u[m] += xv * ((m < 4) ? r0[m] : r1[m - 4]);
    }
#pragma unroll
    for (int m = 0; m < D3; ++m) acc[m] += wv_[ei] * u[m];
  }

  __hip_bfloat16* mo = m_out + (size_t)n * MROW + Rc + rank * NCH + c;
  if (first) {
#pragma unroll
    for (int m = 0; m < D3; ++m) mo[m * Kc] = __float2bfloat16(acc[m]);
  } else {
#pragma unroll
    for (int m = 0; m < D3; ++m)
      mo[m * Kc] = __float2bfloat16(__bfloat162float(mo[m * Kc]) + acc[m]);
  }
}

__global__ __launch_bounds__(256) void tp_node_kernel(
    const float* __restrict__ y0, const float* __restrict__ y1,
    const float* __restrict__ y2, const float* __restrict__ y3,
    const float* __restrict__ ws, const unsigned short* __restrict__ xT,
    const float* __restrict__ cg_pack,
    const int* __restrict__ off, const int* __restrict__ pack,
    const int* __restrict__ order,
    __hip_bfloat16* __restrict__ m_out)
{
  __shared__ float Ts[EBLK][GLEN_MAX];   // 18 KB
  __shared__ float y_s[EBLK][18];
  __shared__ int epk[EBLK];

  const int bid = blockIdx.x;
  const int n = order[bid >> 1];
  const int g = bid & 1;
  const int t = threadIdx.x;
  const int beg = off[n];
  const int cnt = off[n + 1] - beg;
  const int gbase = d_tb.gbase3[g];
  const int glen  = d_tb.glen3[g];
  const int ntask = d_tb.gnp[g] << 6;
  const float* __restrict__ metaf = cg_pack + TT3 * 8;

  for (int base = 0; base == 0 || base < cnt; base += EBLK) {
    int nb = cnt - base;
    nb = nb < 0 ? 0 : (nb > EBLK ? EBLK : nb);
    if (t < nb) epk[t] = pack[beg + base + t];
    if (t >= 64 && t < 64 + 2 * EBLK) y_s[(t - 64) >> 1][16 + (t & 1)] = 0.f;
    __syncthreads();
    if (t < nb * 16) {
      const int ei = t >> 4, j = t & 15;
      const int e = epk[ei] & 8191;
      float v;
      if (j < 1)      v = y0[e];
      else if (j < 4) v = y1[e * 3 + (j - 1)];
      else if (j < 9) v = y2[e * 5 + (j - 4)];
      else            v = y3[e * 7 + (j - 9)];
      y_s[ei][j] = v;
    }
    __syncthreads();
    for (int ei = 0; ei < nb; ++ei) {
      for (int j = t; j < glen; j += 256) {
        const int slot = gbase + j;
        const float4 a = *(const float4*)(cg_pack + slot * 8);
        const float4 c4 = *(const float4*)(cg_pack + slot * 8 + 4);
        const int yb = (int)metaf[slot];
        const float* yy = &y_s[ei][yb];
        Ts[ei][j] = a.x * yy[0] + a.y * yy[1] + a.z * yy[2] + a.w * yy[3]
                  + c4.x * yy[4] + c4.y * yy[5] + c4.z * yy[6] + c4.w * yy[7];
      }
    }
    __syncthreads();

    const bool first = (base == 0);
    for (int k = 0; k * 256 + t < ntask; ++k) {
      const int tl = k * 256 + t;
      const int i = d_tb.gpaths[g][tl >> 6];   // wave-uniform
      const int wcol = (i << 6) | (tl & 63);
      const int toff_l = d_tb.t_off3[i] - gbase;
      const int rk = d_tb.rank[i];
      const int code = d_tb.l1[i] * 4 + d_tb.l3[i];
      switch (code) {
        case  0: tp_task_run<1,1>(wcol, toff_l, rk, nb, epk, Ts, ws, xT, n, first, m_out); break;
        case  1: tp_task_run<1,3>(wcol, toff_l, rk, nb, epk, Ts, ws, xT, n, first, m_out); break;
        case  2: tp_task_run<1,5>(wcol, toff_l, rk, nb, epk, Ts, ws, xT, n, first, m_out); break;
        case  3: tp_task_run<1,7>(wcol, toff_l, rk, nb, epk, Ts, ws, xT, n, first, m_out); break;
        case  4: tp_task_run<3,1>(wcol, toff_l, rk, nb, epk, Ts, ws, xT, n, first, m_out); break;
        case  5: tp_task_run<3,3>(wcol, toff_l, rk, nb, epk, Ts, ws, xT, n, first, m_out); break;
        case  6: tp_task_run<3,5>(wcol, toff_l, rk, nb, epk, Ts, ws, xT, n, first, m_out); break;
        case  7: tp_task_run<3,7>(wcol, toff_l, rk, nb, epk, Ts, ws, xT, n, first, m_out); break;
        case  8: tp_task_run<5,1>(wcol, toff_l, rk, nb, epk, Ts, ws, xT, n, first, m_out); break;
        case  9: tp_task_run<5,3>(wcol, toff_l, rk, nb, epk, Ts, ws, xT, n, first, m_out); break;
        case 10: tp_task_run<5,5>(wcol, toff_l, rk, nb, epk, Ts, ws, xT, n, first, m_out); break;
        case 11: tp_task_run<5,7>(wcol, toff_l, rk, nb, epk, Ts, ws, xT, n, first, m_out); break;
        case 12: tp_task_run<7,1>(wcol, toff_l, rk, nb, epk, Ts, ws, xT, n, first, m_out); break;
        case 13: tp_task_run<7,3>(wcol, toff_l, rk, nb, epk, Ts, ws, xT, n, first, m_out); break;
        case 14: tp_task_run<7,5>(wcol, toff_l, rk, nb, epk, Ts, ws, xT, n, first, m_out); break;
        default: tp_task_run<7,7>(wcol, toff_l, rk, nb, epk, Ts, ws, xT, n, first, m_out); break;
      }
    }
    __syncthreads();
  }
}

// ---------------- kernel 2: fused per-l3 linear — MFMA, no LDS, direct-global frags ----------------
template <int D3, int K, int ROFF>
__device__ __forceinline__ void lin_mfma_body(
    int blk, const unsigned short* __restrict__ mu, const unsigned short* __restrict__ wt,
    float* __restrict__ out)
{
  const int t = threadIdx.x;
  const int wv = t >> 6;
  const int lane = t & 63;
  const int idx16 = lane & 15;
  const int quad = lane >> 4;

  // A-fragment row for this lane: A[m=lane&15][k=quad*8+j]
  const int arow = blk * 64 + wv * 16 + idx16;
  const int ann = arow / D3, amm = arow - ann * D3;
  const unsigned short* __restrict__ ap = mu + (size_t)ann * MROW + ROFF + amm * K + quad * 8;
  const unsigned short* __restrict__ bp = wt + idx16 * K + quad * 8;

  floatx4 acc[4] = {{0.f,0.f,0.f,0.f},{0.f,0.f,0.f,0.f},{0.f,0.f,0.f,0.f},{0.f,0.f,0.f,0.f}};

  for (int k0 = 0; k0 < K; k0 += 32) {
    const short8 af = *(const short8*)(ap + k0);
#pragma unroll
    for (int nt = 0; nt < 4; ++nt) {
      const short8 bf = *(const short8*)(bp + nt * 16 * K + k0);
      acc[nt] = __builtin_amdgcn_mfma_f32_16x16x32_bf16(af, bf, acc[nt], 0, 0, 0);
    }
  }

#pragma unroll
  for (int nt = 0; nt < 4; ++nt) {
    const int h = nt * 16 + idx16;
#pragma unroll
    for (int r = 0; r < 4; ++r) {
      const int row = blk * 64 + wv * 16 + quad * 4 + r;
      const int nn = row / D3, mm = row - nn * D3;
      out[((size_t)nn * NHID + h) * D3 + mm] = acc[nt][r];
    }
  }
}

__global__ __launch_bounds__(256) void lin_fused_kernel(
    const unsigned short* __restrict__ mu, const unsigned short* __restrict__ wt_all,
    float* __restrict__ out)
{
  const int b = blockIdx.x;
  if (b < 32)       lin_mfma_body<1, 256, 0>   (b,       mu, wt_all,         out);
  else if (b < 128) lin_mfma_body<3, 576, 256> (b - 32,  mu, wt_all + 16384, out + 131072);
  else if (b < 288) lin_mfma_body<5, 704, 1984>(b - 128, mu, wt_all + 53248, out + 524288);
  else              lin_mfma_body<7, 640, 5504>(b - 288, mu, wt_all + 98304, out + 1179648);
}

// ---------------- launch ----------------
extern "C" void kernel_launch(void* const* d_in, const int* in_sizes, int n_in,
                              void* d_out, int out_size, void* d_ws, size_t ws_size,
                              hipStream_t stream) {
  const float* x0  = (const float*)d_in[0];
  const float* y0  = (const float*)d_in[1];
  const float* wl0 = (const float*)d_in[2];
  const float* x1  = (const float*)d_in[3];
  const float* y1  = (const float*)d_in[4];
  const float* wl1 = (const float*)d_in[5];
  const float* x2  = (const float*)d_in[6];
  const float* y2  = (const float*)d_in[7];
  const float* wl2 = (const float*)d_in[8];
  const float* x3  = (const float*)d_in[9];
  const float* y3  = (const float*)d_in[10];
  const float* wl3 = (const float*)d_in[11];
  const float* ws  = (const float*)d_in[12];
  const int* edge_index = (const int*)d_in[13];
  float* out = (float*)d_out;

  __hip_bfloat16* m_i = (__hip_bfloat16*)d_ws;
  int* csr_off = (int*)((char*)d_ws + OFF_OFF);
  int* cursor  = (int*)((char*)d_ws + CUR_OFF);
  int* pack    = (int*)((char*)d_ws + PACK_OFF);
  int* order   = (int*)((char*)d_ws + ORD_OFF);
  __hip_bfloat16* xT = (__hip_bfloat16*)((char*)d_ws + XT_OFF);
  unsigned short* wt_all = (unsigned short*)((char*)d_ws + WT_OFF);

  const float* cg_pack;
  if (g_cg_ok) {
    cg_pack = g_cg_dev;
  } else {
    float* cg_ws = (float*)((char*)d_ws + CGP_OFF);
    hipMemcpyAsync(cg_ws, host_pack, sizeof(host_pack), hipMemcpyHostToDevice, stream);
    cg_pack = cg_ws;
  }

  scan_kernel<<<1, 1024, 0, stream>>>(edge_index, csr_off, cursor, order);
  fill_xt_kernel<<<32 + NNODES + 544, 256, 0, stream>>>(edge_index, cursor, pack,
                                                        x0, x1, x2, x3,
                                                        wl0, wl1, wl2, wl3,
                                                        xT, wt_all);
  tp_node_kernel<<<2 * NNODES, 256, 0, stream>>>(y0, y1, y2, y3, ws,
                                                 (const unsigned short*)xT, cg_pack,
                                                 csr_off, pack, order, m_i);
  lin_fused_kernel<<<512, 256, 0, stream>>>((const unsigned short*)m_i, wt_all, out);
}